// Round 1
// baseline (493.238 us; speedup 1.0000x reference)
//
#include <hip/hip_runtime.h>

// Problem: B=1024, H=56, J=64 (channel group), N=56, I=64 output channels.
// t4[b,i,m,n] = sum_{k,j} x[b, m+k-1, j, n] * W2[i,k,j]   (zero-padded in h)
// y[b,i,m,(n+1)%56] = t4[b,i,m,n]*W1[i,0] + t4[b,i,(m-1)%56,n]*W1[i,1]

#define HH 56
#define JJ 64
#define NN 56

// LDS: transposed x slices, bf16. Layout [n(64 rows)][slot(4)][j(64)]
// row stride 264 ushorts = 528 B (16B aligned, breaks 32-bank power-of-2 stride)
#define ROWE 264
#define SLOTE 64

typedef __attribute__((ext_vector_type(8))) short short8_t;
typedef __attribute__((ext_vector_type(4))) short short4_t;
typedef __attribute__((ext_vector_type(4))) float f32x4;

__device__ __forceinline__ unsigned short f2bf(float f) {
  union { float f; unsigned u; } v; v.f = f;
  // round-to-nearest-even fp32 -> bf16
  return (unsigned short)((v.u + 0x7FFFu + ((v.u >> 16) & 1u)) >> 16);
}

__global__ __launch_bounds__(256, 1) void fused_conv_mix_kernel(
    const float* __restrict__ x, const float* __restrict__ W1,
    const float* __restrict__ W2, float* __restrict__ out) {
  __shared__ unsigned short lds[64 * ROWE];

  const int tid  = threadIdx.x;
  const int wave = tid >> 6;   // 4 waves; wave w owns output rows i in [16w,16w+16)
  const int lane = tid & 63;
  const int lq   = lane & 15;  // MFMA: A row / B col / D col index
  const int lg   = lane >> 4;  // MFMA lane group

  const int b = blockIdx.x;
  const float* __restrict__ xb   = x + (size_t)b * HH * JJ * NN;
  float* __restrict__       outb = out + (size_t)b * 64 * HH * NN;

  // ---- A fragments: W2[i, k, j] as 64 x (kj=192) bf16, resident in VGPRs ----
  // kstep s covers kj in [32s, 32s+32): k = s>>1, j = (s&1)*32 + lg*8 + e
  short8_t afrag[6];
  {
    const int i = 16 * wave + lq;
    #pragma unroll
    for (int s = 0; s < 6; ++s) {
      const int kk = s >> 1;
      const int j0 = (s & 1) * 32 + lg * 8;
      const float* p = W2 + ((size_t)i * 3 + kk) * 64 + j0;
      short8_t a;
      #pragma unroll
      for (int e = 0; e < 8; ++e) a[e] = (short)f2bf(p[e]);
      afrag[s] = a;
    }
  }

  // ---- W1 per-lane (i = 16*wave + lg*4 + r, matching D-fragment rows) ----
  float w1a[4], w1b[4];
  {
    const int ibase = 16 * wave + lg * 4;
    #pragma unroll
    for (int r = 0; r < 4; ++r) {
      w1a[r] = W1[(ibase + r) * 2 + 0];
      w1b[r] = W1[(ibase + r) * 2 + 1];
    }
  }

  // ---- stage one h-slice into LDS ring (transposed, fp32->bf16) ----
  // 224 work items: j-quad (16) x n-quad (14). Each: 4x global float4 loads,
  // 4x4 in-register transpose, 4x ds_write_b64.
  auto stage = [&](int h) {
    if (tid < 224) {
      const int slot = (h + 4) & 3;
      const int j4 = tid / 14;
      const int n4 = tid - j4 * 14;
      const int j  = j4 * 4;
      const int n0 = n4 * 4;
      short4_t v0, v1, v2, v3;
      if (h >= 0 && h < HH) {
        const float* p = xb + ((size_t)h * JJ + j) * NN + n0;
        const float4 r0 = *(const float4*)(p);
        const float4 r1 = *(const float4*)(p + NN);
        const float4 r2 = *(const float4*)(p + 2 * NN);
        const float4 r3 = *(const float4*)(p + 3 * NN);
        v0[0] = (short)f2bf(r0.x); v0[1] = (short)f2bf(r1.x); v0[2] = (short)f2bf(r2.x); v0[3] = (short)f2bf(r3.x);
        v1[0] = (short)f2bf(r0.y); v1[1] = (short)f2bf(r1.y); v1[2] = (short)f2bf(r2.y); v1[3] = (short)f2bf(r3.y);
        v2[0] = (short)f2bf(r0.z); v2[1] = (short)f2bf(r1.z); v2[2] = (short)f2bf(r2.z); v2[3] = (short)f2bf(r3.z);
        v3[0] = (short)f2bf(r0.w); v3[1] = (short)f2bf(r1.w); v3[2] = (short)f2bf(r2.w); v3[3] = (short)f2bf(r3.w);
      } else {
        short4_t z = {0, 0, 0, 0};
        v0 = z; v1 = z; v2 = z; v3 = z;
      }
      unsigned short* base = &lds[(size_t)n0 * ROWE + slot * SLOTE + j];
      *(short4_t*)(base)            = v0;
      *(short4_t*)(base + ROWE)     = v1;
      *(short4_t*)(base + 2 * ROWE) = v2;
      *(short4_t*)(base + 3 * ROWE) = v3;
    }
  };

  // ---- one m-step GEMM: acc[t] = W2 * X_m, t indexes n-tiles of 16 ----
  auto compute = [&](int m, f32x4* acc) {
    #pragma unroll
    for (int t = 0; t < 4; ++t) { acc[t][0] = 0.f; acc[t][1] = 0.f; acc[t][2] = 0.f; acc[t][3] = 0.f; }
    #pragma unroll
    for (int s = 0; s < 6; ++s) {
      const int h    = m - 1 + (s >> 1);
      const int slot = (h + 4) & 3;
      const int off  = slot * SLOTE + (s & 1) * 32 + lg * 8;
      #pragma unroll
      for (int t = 0; t < 4; ++t) {
        const int n = lq + 16 * t;
        const short8_t bf = *(const short8_t*)&lds[(size_t)n * ROWE + off];
        acc[t] = __builtin_amdgcn_mfma_f32_16x16x32_bf16(afrag[s], bf, acc[t], 0, 0, 0);
      }
    }
  };

  f32x4 prev[4], cur[4];

  // Prologue A: compute t4[55] (the m-roll wrap source). Needs h=54,55,56(zero).
  stage(54); stage(55); stage(56);
  __syncthreads();
  compute(55, prev);
  __syncthreads();
  // Prologue B: slices for m=0: h=-1(zero),0,1
  stage(-1); stage(0); stage(1);
  __syncthreads();

  for (int m = 0; m < HH; ++m) {
    // prefetch slice h=m+2 (slot (m+2)&3, disjoint from the 3 compute slots)
    if (m + 2 <= HH) stage(m + 2);   // h=56 stages zeros
    compute(m, cur);
    // fused epilogue: W1 mix along m + circular +1 roll along n
    #pragma unroll
    for (int t = 0; t < 4; ++t) {
      const int n = lq + 16 * t;
      if (n < NN) {
        const int nout = (n + 1 == NN) ? 0 : (n + 1);
        #pragma unroll
        for (int r = 0; r < 4; ++r) {
          const int i = 16 * wave + lg * 4 + r;
          outb[((size_t)i * HH + m) * NN + nout] = cur[t][r] * w1a[r] + prev[t][r] * w1b[r];
        }
      }
      prev[t] = cur[t];
    }
    __syncthreads();
  }
}

extern "C" void kernel_launch(void* const* d_in, const int* in_sizes, int n_in,
                              void* d_out, int out_size, void* d_ws, size_t ws_size,
                              hipStream_t stream) {
  const float* x  = (const float*)d_in[0];
  const float* W1 = (const float*)d_in[1];
  const float* W2 = (const float*)d_in[2];
  float* out = (float*)d_out;
  fused_conv_mix_kernel<<<1024, 256, 0, stream>>>(x, W1, W2, out);
}

// Round 2
// 447.230 us; speedup vs baseline: 1.1029x; 1.1029x over previous
//
#include <hip/hip_runtime.h>

// B=1024, H=56, J=64, N=56, I=64.
// t4[b,i,m,n] = sum_{k,j} x[b, m+k-1, j, n] * W2[i,k,j]   (zero-padded in h)
// y[b,i,m,(n+1)%56] = t4[b,i,m,n]*W1[i,0] + t4[b,i,(m-1)%56,n]*W1[i,1]
//
// Pipeline per iteration m (raw barrier, counted-wait discipline):
//   compute(m) from LDS slots {m-1,m,m+1};  ds_write slice m+2 from regs
//   (loaded one full iteration ago);  issue global loads for slice m+3;
//   epilogue stores y[m];  lgkmcnt(0) + s_barrier (NO vmcnt drain -> loads
//   stay in flight across the barrier).

#define HH 56
#define JJ 64
#define NN 56

// LDS ring: 4 slots, transposed bf16. [n(64 rows)][slot(4)][j(64)]
// row stride 264 ushorts = 528 B (16B-aligned, non-power-of-2)
#define ROWE 264
#define SLOTE 64

typedef __attribute__((ext_vector_type(8))) short short8_t;
typedef __attribute__((ext_vector_type(4))) short short4_t;
typedef __attribute__((ext_vector_type(4))) float f32x4;

__device__ __forceinline__ unsigned short f2bf(float f) {
  union { float f; unsigned u; } v; v.f = f;
  return (unsigned short)((v.u + 0x7FFFu + ((v.u >> 16) & 1u)) >> 16);
}

__global__ __launch_bounds__(256, 4) void fused_conv_mix_kernel(
    const float* __restrict__ x, const float* __restrict__ W1,
    const float* __restrict__ W2, float* __restrict__ out) {
  __shared__ unsigned short lds[64 * ROWE];

  const int tid  = threadIdx.x;
  const int wave = tid >> 6;
  const int lane = tid & 63;
  const int lq   = lane & 15;
  const int lg   = lane >> 4;

  const int b = blockIdx.x;
  const float* __restrict__ xb   = x + (size_t)b * HH * JJ * NN;
  float* __restrict__       outb = out + (size_t)b * 64 * HH * NN;

  // ---- A fragments: W2[i,k,j] as 64 x 192 bf16, resident in VGPRs ----
  short8_t afrag[6];
  {
    const int i = 16 * wave + lq;
    #pragma unroll
    for (int s = 0; s < 6; ++s) {
      const int kk = s >> 1;
      const int j0 = (s & 1) * 32 + lg * 8;
      const float* p = W2 + ((size_t)i * 3 + kk) * 64 + j0;
      short8_t a;
      #pragma unroll
      for (int e = 0; e < 8; ++e) a[e] = (short)f2bf(p[e]);
      afrag[s] = a;
    }
  }

  // ---- W1 per-lane (i = 16*wave + lg*4 + r matches D rows) ----
  float w1a[4], w1b[4];
  size_t obase[4];
  {
    const int ibase = 16 * wave + lg * 4;
    #pragma unroll
    for (int r = 0; r < 4; ++r) {
      w1a[r] = W1[(ibase + r) * 2 + 0];
      w1b[r] = W1[(ibase + r) * 2 + 1];
      obase[r] = (size_t)(ibase + r) * HH * NN;
    }
  }

  // staging coords: 224 workers, j-quad x n-quad
  const int sj  = (tid / 14) * 4;
  const int sn0 = (tid % 14) * 4;
  unsigned short* const sbase0 = &lds[(size_t)sn0 * ROWE + sj];

  // issue global loads (or zeros) for slice h into R[0..3]; NO wait here
  auto issue = [&](int h, float4* R) {
    if (h <= HH && tid < 224) {
      if (h >= 0 && h < HH) {
        const float* p = xb + ((size_t)h * JJ + sj) * NN + sn0;
        R[0] = *(const float4*)(p);
        R[1] = *(const float4*)(p + NN);
        R[2] = *(const float4*)(p + 2 * NN);
        R[3] = *(const float4*)(p + 3 * NN);
      } else {
        float4 z = {0.f, 0.f, 0.f, 0.f};
        R[0] = z; R[1] = z; R[2] = z; R[3] = z;
      }
    }
  };

  // convert+transpose R -> LDS slot of slice h (compiler inserts the vmcnt)
  auto put = [&](int h, const float4* R) {
    if (h <= HH && tid < 224) {
      const int slot = (h + 4) & 3;
      short4_t v0, v1, v2, v3;
      v0[0] = (short)f2bf(R[0].x); v0[1] = (short)f2bf(R[1].x); v0[2] = (short)f2bf(R[2].x); v0[3] = (short)f2bf(R[3].x);
      v1[0] = (short)f2bf(R[0].y); v1[1] = (short)f2bf(R[1].y); v1[2] = (short)f2bf(R[2].y); v1[3] = (short)f2bf(R[3].y);
      v2[0] = (short)f2bf(R[0].z); v2[1] = (short)f2bf(R[1].z); v2[2] = (short)f2bf(R[2].z); v2[3] = (short)f2bf(R[3].z);
      v3[0] = (short)f2bf(R[0].w); v3[1] = (short)f2bf(R[1].w); v3[2] = (short)f2bf(R[2].w); v3[3] = (short)f2bf(R[3].w);
      unsigned short* base = sbase0 + slot * SLOTE;
      *(short4_t*)(base)            = v0;
      *(short4_t*)(base + ROWE)     = v1;
      *(short4_t*)(base + 2 * ROWE) = v2;
      *(short4_t*)(base + 3 * ROWE) = v3;
    }
  };

  auto compute = [&](int m, f32x4* acc) {
    #pragma unroll
    for (int t = 0; t < 4; ++t) { acc[t][0] = 0.f; acc[t][1] = 0.f; acc[t][2] = 0.f; acc[t][3] = 0.f; }
    #pragma unroll
    for (int s = 0; s < 6; ++s) {
      const int h    = m - 1 + (s >> 1);
      const int slot = (h + 4) & 3;
      const int off  = slot * SLOTE + (s & 1) * 32 + lg * 8;
      #pragma unroll
      for (int t = 0; t < 4; ++t) {
        const int n = lq + 16 * t;
        const short8_t bf = *(const short8_t*)&lds[(size_t)n * ROWE + off];
        acc[t] = __builtin_amdgcn_mfma_f32_16x16x32_bf16(afrag[s], bf, acc[t], 0, 0, 0);
      }
    }
  };

  // mix along m (W1), rotate +1 along n in-register, aligned stores
  auto epilogue = [&](int m, const f32x4* cur, const f32x4* prv) {
    f32x4 val[4];
    #pragma unroll
    for (int t = 0; t < 4; ++t)
      #pragma unroll
      for (int r = 0; r < 4; ++r)
        val[t][r] = cur[t][r] * w1a[r] + prv[t][r] * w1b[r];
    const int src  = (lane & 48) | ((lane + 15) & 15);  // lane lq-1 (15 for lq==0)
    const int src7 = (lane & 48) | 7;                   // lane holding n=55 (t=3)
    float rot[4][4], spec[4];
    #pragma unroll
    for (int t = 0; t < 4; ++t)
      #pragma unroll
      for (int r = 0; r < 4; ++r)
        rot[t][r] = __shfl(val[t][r], src, 64);
    #pragma unroll
    for (int r = 0; r < 4; ++r) spec[r] = __shfl(val[3][r], src7, 64);
    const size_t moff = (size_t)m * NN;
    #pragma unroll
    for (int t = 0; t < 4; ++t) {
      const int c = 16 * t + lq;     // output column, aligned segments
      if (c < NN) {
        #pragma unroll
        for (int r = 0; r < 4; ++r) {
          const float v = lq ? rot[t][r] : (t ? rot[t - 1][r] : spec[r]);
          outb[obase[r] + moff + c] = v;
        }
      }
    }
  };

  f32x4 acc0[4], acc1[4];
  float4 R[4];

  // ---- prologue: t4[55] (m-roll wrap source), then slices for m=0 ----
  {
    float4 Ra[4], Rb[4], Rc[4];
    issue(54, Ra); issue(55, Rb); issue(56, Rc);
    put(54, Ra); put(55, Rb); put(56, Rc);
    __syncthreads();
    compute(55, acc1);
    __syncthreads();          // all reads done before slot reuse
    issue(-1, Ra); issue(0, Rb); issue(1, Rc);
    put(-1, Ra); put(0, Rb); put(1, Rc);
    __syncthreads();
  }
  issue(2, R);

  // ---- main loop, 2-unrolled for static acc ping-pong ----
  #pragma unroll 1
  for (int m = 0; m < HH; m += 2) {
    // even: cur=acc0, prev=acc1
    compute(m, acc0);
    put(m + 2, R);            // slice loaded one iteration ago
    issue(m + 3, R);          // stays in flight across the barrier
    epilogue(m, acc0, acc1);
    asm volatile("s_waitcnt lgkmcnt(0)" ::: "memory");
    __builtin_amdgcn_s_barrier();
    __builtin_amdgcn_sched_barrier(0);
    // odd: cur=acc1, prev=acc0
    compute(m + 1, acc1);
    put(m + 3, R);
    issue(m + 4, R);
    epilogue(m + 1, acc1, acc0);
    asm volatile("s_waitcnt lgkmcnt(0)" ::: "memory");
    __builtin_amdgcn_s_barrier();
    __builtin_amdgcn_sched_barrier(0);
  }
}

extern "C" void kernel_launch(void* const* d_in, const int* in_sizes, int n_in,
                              void* d_out, int out_size, void* d_ws, size_t ws_size,
                              hipStream_t stream) {
  const float* x  = (const float*)d_in[0];
  const float* W1 = (const float*)d_in[1];
  const float* W2 = (const float*)d_in[2];
  float* out = (float*)d_out;
  fused_conv_mix_kernel<<<1024, 256, 0, stream>>>(x, W1, W2, out);
}